// Round 1
// baseline (204.007 us; speedup 1.0000x reference)
//
#include <hip/hip_runtime.h>
#include <math.h>

// Problem constants (fixed by the reference)
#define KP   512     // n_primitives
#define DD   64      // view_dim
#define BB   4096    // batch
#define NTRI 2016    // D*(D-1)/2

// ws layout (floats):
//   Lws   : KP * 4096   (per-k dense 64x64 Cholesky, COLUMN-major: Lc[e*64+d] = L[d][e])
//   wws   : KP * 64     (w_k[e] = sum_{d>=e} mu_k[d] * L_k[d][e])
//   biasws: KP          (log(softplus(log_s)+1e-8))
//   mahal : BB * KP
// total = (512*4096 + 512*64 + 512 + 4096*512)*4 B ~= 16.1 MiB

__global__ __launch_bounds__(256) void prep_kernel(
    const float* __restrict__ mu, const float* __restrict__ log_diag,
    const float* __restrict__ log_s, const float* __restrict__ lod,
    float* __restrict__ Lws, float* __restrict__ wws, float* __restrict__ biasws)
{
    const int k = blockIdx.x;
    const int tid = threadIdx.x;
    __shared__ float Lc[64 * 64];   // column-major
    __shared__ float muS[64];

    for (int idx = tid; idx < 4096; idx += 256) Lc[idx] = 0.0f;
    if (tid < 64) muS[tid] = mu[k * 64 + tid];
    __syncthreads();

    // diagonal: L[d][d] = exp(0.5*log_diag)
    if (tid < 64) Lc[tid * 64 + tid] = expf(0.5f * log_diag[k * 64 + tid]);
    // off-diagonal: tril_indices(D, -1) row-major: t = i*(i-1)/2 + j, i>j
    for (int t = tid; t < NTRI; t += 256) {
        int i = (int)((1.0f + sqrtf(8.0f * (float)t + 1.0f)) * 0.5f);
        while (i * (i - 1) / 2 > t) --i;
        while ((i + 1) * i / 2 <= t) ++i;
        int j = t - i * (i - 1) / 2;
        Lc[j * 64 + i] = lod[(size_t)k * NTRI + t];   // col j, row i
    }
    __syncthreads();

    // w_e = sum_{d>=e} mu[d] * L[d][e]
    if (tid < 64) {
        const int e = tid;
        float s = 0.0f;
        for (int d = e; d < 64; ++d) s += muS[d] * Lc[e * 64 + d];
        wws[k * 64 + e] = s;
    }
    // dump L to ws (coalesced)
    for (int idx = tid; idx < 4096; idx += 256)
        Lws[(size_t)k * 4096 + idx] = Lc[idx];

    if (tid == 0) {
        float s = log_s[k];
        float sp = (s > 20.0f) ? s : log1pf(expf(s));   // stable softplus
        biasws[k] = logf(sp + 1e-8f);
    }
}

// Each block: 256 consecutive b rows x 2 consecutive k's.
// z row lives in 64 VGPRs (all indices compile-time via full unroll);
// L columns are wave-uniform LDS broadcasts (b128).
__global__ __launch_bounds__(256) void mahal_kernel(
    const float* __restrict__ z, const float* __restrict__ Lws,
    const float* __restrict__ wws, float* __restrict__ mahal)
{
    const int tid = threadIdx.x;
    const int b = blockIdx.x * 256 + tid;
    const int k0 = blockIdx.y * 2;

    __shared__ float Lc[2 * 4096];   // 32 KB
    __shared__ float wS[2 * 64];

    for (int idx = tid; idx < 2 * 4096; idx += 256)
        Lc[idx] = Lws[(size_t)k0 * 4096 + idx];
    if (tid < 128) wS[tid] = wws[k0 * 64 + tid];
    __syncthreads();

    float zr[64];
    const float4* zp = (const float4*)(z + (size_t)b * 64);
#pragma unroll
    for (int j = 0; j < 16; ++j) {
        float4 v = zp[j];
        zr[4 * j + 0] = v.x; zr[4 * j + 1] = v.y;
        zr[4 * j + 2] = v.z; zr[4 * j + 3] = v.w;
    }

#pragma unroll 1   // keep the ~2.7K-inst body I$-resident; re-run it per k
    for (int kk = 0; kk < 2; ++kk) {
        const float* Lk = &Lc[kk * 4096];
        const float* wk = &wS[kk * 64];
        float m = 0.0f;
#pragma unroll
        for (int e = 0; e < 64; ++e) {
            const int d0 = e & ~3;          // 16B-aligned start; upper-tri is zero
            float t0 = -wk[e];
            float t1 = 0.0f;
#pragma unroll
            for (int d = d0; d < 64; d += 4) {
                float4 L4 = *(const float4*)(Lk + e * 64 + d);
                t0 = fmaf(zr[d + 0], L4.x, t0);
                t1 = fmaf(zr[d + 1], L4.y, t1);
                t0 = fmaf(zr[d + 2], L4.z, t0);
                t1 = fmaf(zr[d + 3], L4.w, t1);
            }
            float t = t0 + t1;
            m = fmaf(t, t, m);
        }
        mahal[(size_t)b * KP + k0 + kk] = m;
    }
}

__global__ __launch_bounds__(256) void softmax_kernel(
    const float* __restrict__ mahal, const float* __restrict__ biasws,
    float* __restrict__ alpha)
{
    const int b = blockIdx.x;
    const int tid = threadIdx.x;
    const float* mrow = mahal + (size_t)b * KP;

    float la0 = -0.5f * mrow[tid]       + biasws[tid];
    float la1 = -0.5f * mrow[tid + 256] + biasws[tid + 256];

    float lm = fmaxf(la0, la1);
#pragma unroll
    for (int off = 32; off >= 1; off >>= 1)
        lm = fmaxf(lm, __shfl_xor(lm, off, 64));

    __shared__ float red[8];
    const int wid = tid >> 6;
    const int lane = tid & 63;
    if (lane == 0) red[wid] = lm;
    __syncthreads();
    const float M = fmaxf(fmaxf(red[0], red[1]), fmaxf(red[2], red[3]));

    float a0 = expf(la0 - M);
    float a1 = expf(la1 - M);
    float s = a0 + a1;
#pragma unroll
    for (int off = 32; off >= 1; off >>= 1)
        s += __shfl_xor(s, off, 64);
    if (lane == 0) red[4 + wid] = s;
    __syncthreads();
    const float S = red[4] + red[5] + red[6] + red[7];

    const float r = 1.0f / (S + 1e-8f);
    alpha[(size_t)b * KP + tid]       = a0 * r;
    alpha[(size_t)b * KP + tid + 256] = a1 * r;
}

extern "C" void kernel_launch(void* const* d_in, const int* in_sizes, int n_in,
                              void* d_out, int out_size, void* d_ws, size_t ws_size,
                              hipStream_t stream) {
    const float* z        = (const float*)d_in[0];   // (B, D)
    const float* mu       = (const float*)d_in[1];   // (K, D)
    const float* log_diag = (const float*)d_in[2];   // (K, D)
    const float* log_s    = (const float*)d_in[3];   // (K,)
    const float* lod      = (const float*)d_in[4];   // (K, 2016)
    float* out = (float*)d_out;                      // (B, K)

    float* Lws    = (float*)d_ws;
    float* wws    = Lws + (size_t)KP * 4096;
    float* biasws = wws + (size_t)KP * 64;
    float* mahalws = biasws + KP;

    prep_kernel<<<KP, 256, 0, stream>>>(mu, log_diag, log_s, lod, Lws, wws, biasws);
    mahal_kernel<<<dim3(BB / 256, KP / 2), 256, 0, stream>>>(z, Lws, wws, mahalws);
    softmax_kernel<<<BB, 256, 0, stream>>>(mahalws, biasws, out);
}

// Round 3
// 62.271 us; speedup vs baseline: 3.2761x; 3.2761x over previous
//
#include <hip/hip_runtime.h>
#include <hip/hip_bf16.h>
#include <math.h>

#define KP   512
#define DD   64
#define BB   4096
#define NTRI 2016

typedef __attribute__((ext_vector_type(8))) short bfrag;    // 8 bf16 (4 VGPRs)
typedef __attribute__((ext_vector_type(4))) float facc4;    // 16x16 MFMA accumulator

// ws layout (bytes):
//   Limg  : KP * 16384   per k: hi plane 8KB ([e][d] bf16 row-major), lo plane 8KB
//   wws   : KP * 64 * 4
//   biasws: KP * 4
//   mahal : BB * KP * 4

__device__ __forceinline__ void async16(const void* g, void* l) {
    __builtin_amdgcn_global_load_lds(
        (const __attribute__((address_space(1))) unsigned int*)g,
        (__attribute__((address_space(3))) unsigned int*)l, 16, 0, 0);
}

__global__ __launch_bounds__(256) void prep_kernel(
    const float* __restrict__ mu, const float* __restrict__ log_diag,
    const float* __restrict__ log_s, const float* __restrict__ lod,
    unsigned short* __restrict__ Limg, float* __restrict__ wws,
    float* __restrict__ biasws)
{
    const int k = blockIdx.x;
    const int tid = threadIdx.x;
    __shared__ float Lc[64 * 64];   // Lc[e*64 + d] = L[d][e]  (row-major [e][d] of L^T)
    __shared__ float muS[64];

    for (int idx = tid; idx < 4096; idx += 256) Lc[idx] = 0.0f;
    if (tid < 64) muS[tid] = mu[k * 64 + tid];
    __syncthreads();

    if (tid < 64) Lc[tid * 64 + tid] = expf(0.5f * log_diag[k * 64 + tid]);
    for (int t = tid; t < NTRI; t += 256) {
        int i = (int)((1.0f + sqrtf(8.0f * (float)t + 1.0f)) * 0.5f);
        while (i * (i - 1) / 2 > t) --i;
        while ((i + 1) * i / 2 <= t) ++i;
        int j = t - i * (i - 1) / 2;
        Lc[j * 64 + i] = lod[(size_t)k * NTRI + t];   // L[i][j], i>j
    }
    __syncthreads();

    // w_e = sum_{d>=e} mu[d] * L[d][e]
    if (tid < 64) {
        const int e = tid;
        float s = 0.0f;
        for (int d = e; d < 64; ++d) s += muS[d] * Lc[e * 64 + d];
        wws[k * 64 + e] = s;
    }
    // hi/lo bf16 planes, row-major [e][d]
    for (int idx = tid; idx < 4096; idx += 256) {
        float v = Lc[idx];
        __hip_bfloat16 hb = __float2bfloat16(v);
        float hv = __bfloat162float(hb);
        __hip_bfloat16 lb = __float2bfloat16(v - hv);
        Limg[(size_t)k * 8192 + idx]        = *(unsigned short*)&hb;
        Limg[(size_t)k * 8192 + 4096 + idx] = *(unsigned short*)&lb;
    }
    if (tid == 0) {
        float s = log_s[k];
        float sp = (s > 20.0f) ? s : log1pf(expf(s));
        biasws[k] = logf(sp + 1e-8f);
    }
}

// T' = L^T Z^T per k, via the m97-verified 16x16x32 bf16 convention:
//   A tile = Lt [e][d] in LDS (linear), frag = 8 contiguous d at row (lane&15)
//   B tile = Z  [b][d] in regs,        frag = 8 contiguous d at row (lane&15)
//   C: col b = lane&15, row e_local = 4*(lane>>4) + reg      (m89/m91 verified)
// mahal[b,k] = sum_e (T'[e,b] - w[e])^2
__global__ __launch_bounds__(256, 2) void mahal_kernel(
    const float* __restrict__ z, const unsigned short* __restrict__ Limg,
    const float* __restrict__ wws, float* __restrict__ mahal)
{
    __shared__ __align__(16) char  ldsImg[16384];   // [2 planes][64 e-rows][128 B] linear
    __shared__ __align__(16) float wS[16 * 64];

    const int tid  = threadIdx.x;
    const int wave = tid >> 6;
    const int lane = tid & 63;
    const int g    = lane >> 4;
    const int l15  = lane & 15;

    // bijective remap: 512 blocks = 32 kslices x 16 bblks; same kslice -> same n%8 (XCD)
    const int n      = blockIdx.x;
    const int kslice = (n & 7) + ((n >> 7) << 3);   // [0,32)
    const int bblk   = (n >> 3) & 15;               // [0,16)
    const int k0     = kslice * 16;
    const int bw     = bblk * 256 + wave * 64;

    // stage w for this kslice (plain, once)
    for (int i = tid; i < 16 * 64; i += 256) wS[i] = wws[k0 * 64 + i];

    // Z fragments (B operand): col b = l15, d = ds*32 + 8*g + j, hi/lo split
    bfrag zh[4][2], zl[4][2];
#pragma unroll
    for (int bs = 0; bs < 4; ++bs) {
        const float* zp = z + (size_t)(bw + bs * 16 + l15) * 64 + 8 * g;
#pragma unroll
        for (int ds = 0; ds < 2; ++ds) {
            float4 a = *(const float4*)(zp + ds * 32);
            float4 c = *(const float4*)(zp + ds * 32 + 4);
            float vv[8] = {a.x, a.y, a.z, a.w, c.x, c.y, c.z, c.w};
            bfrag th, tl;
#pragma unroll
            for (int j = 0; j < 8; ++j) {
                __hip_bfloat16 hb = __float2bfloat16(vv[j]);
                float hv = __bfloat162float(hb);
                __hip_bfloat16 lb = __float2bfloat16(vv[j] - hv);
                th[j] = *(short*)&hb;
                tl[j] = *(short*)&lb;
            }
            zh[bs][ds] = th;
            zl[bs][ds] = tl;
        }
    }

    const char* imgK = (const char*)Limg + (size_t)k0 * 16384;
    // A-frag LDS byte address (linear): plane*8192 + e*128 + ds*64 + 16*g
    const int aoff = l15 * 128 + 16 * g;

    for (int kk = 0; kk < 16; ++kk) {
        // linear staging, m97 pattern: wave-uniform LDS base + lane*16,
        // per-lane contiguous global source
        const char* src = imgK + kk * 16384;
#pragma unroll
        for (int p = 0; p < 4; ++p) {
            const int cof = p * 4096 + wave * 1024;
            async16(src + cof + lane * 16, ldsImg + cof);
        }
        asm volatile("s_waitcnt vmcnt(0)" ::: "memory");
        __syncthreads();

        facc4 acc[4][4];   // [etile][bsub]
#pragma unroll
        for (int et = 0; et < 4; ++et)
#pragma unroll
            for (int bs = 0; bs < 4; ++bs)
#pragma unroll
                for (int r = 0; r < 4; ++r) acc[et][bs][r] = 0.0f;

#pragma unroll
        for (int ds = 0; ds < 2; ++ds) {
#pragma unroll
            for (int et = 0; et < 4; ++et) {
                if (et >= 2 && ds == 0) continue;   // triangular: e>=32 needs d>=32 only
                const int ao = et * 2048 + ds * 64 + aoff;
                bfrag lh = *(const bfrag*)(ldsImg + ao);
                bfrag ll = *(const bfrag*)(ldsImg + 8192 + ao);
#pragma unroll
                for (int bs = 0; bs < 4; ++bs) {
                    acc[et][bs] = __builtin_amdgcn_mfma_f32_16x16x32_bf16(lh, zh[bs][ds], acc[et][bs], 0, 0, 0);
                    acc[et][bs] = __builtin_amdgcn_mfma_f32_16x16x32_bf16(ll, zh[bs][ds], acc[et][bs], 0, 0, 0);
                    acc[et][bs] = __builtin_amdgcn_mfma_f32_16x16x32_bf16(lh, zl[bs][ds], acc[et][bs], 0, 0, 0);
                }
            }
        }

        // epilogue: e = et*16 + 4*g + r
        const float* wrow = wS + kk * 64;
        float4 wv[4];
#pragma unroll
        for (int et = 0; et < 4; ++et)
            wv[et] = *(const float4*)(wrow + et * 16 + 4 * g);

        const int k = k0 + kk;
#pragma unroll
        for (int bs = 0; bs < 4; ++bs) {
            float p0 = 0.f, p1 = 0.f, p2 = 0.f, p3 = 0.f;
#pragma unroll
            for (int et = 0; et < 4; ++et) {
                float t0 = acc[et][bs][0] - wv[et].x; p0 = fmaf(t0, t0, p0);
                float t1 = acc[et][bs][1] - wv[et].y; p1 = fmaf(t1, t1, p1);
                float t2 = acc[et][bs][2] - wv[et].z; p2 = fmaf(t2, t2, p2);
                float t3 = acc[et][bs][3] - wv[et].w; p3 = fmaf(t3, t3, p3);
            }
            float s = (p0 + p1) + (p2 + p3);
            s += __shfl_xor(s, 16, 64);
            s += __shfl_xor(s, 32, 64);
            if (g == 0)
                mahal[(size_t)(bw + bs * 16 + l15) * KP + k] = s;
        }
        __syncthreads();
    }
}

__global__ __launch_bounds__(256) void softmax_kernel(
    const float* __restrict__ mahal, const float* __restrict__ biasws,
    float* __restrict__ alpha)
{
    const int b = blockIdx.x;
    const int tid = threadIdx.x;
    const float* mrow = mahal + (size_t)b * KP;

    float la0 = -0.5f * mrow[tid]       + biasws[tid];
    float la1 = -0.5f * mrow[tid + 256] + biasws[tid + 256];

    float lm = fmaxf(la0, la1);
#pragma unroll
    for (int off = 32; off >= 1; off >>= 1)
        lm = fmaxf(lm, __shfl_xor(lm, off, 64));

    __shared__ float red[8];
    const int wid = tid >> 6;
    const int lane = tid & 63;
    if (lane == 0) red[wid] = lm;
    __syncthreads();
    const float M = fmaxf(fmaxf(red[0], red[1]), fmaxf(red[2], red[3]));

    float a0 = expf(la0 - M);
    float a1 = expf(la1 - M);
    float s = a0 + a1;
#pragma unroll
    for (int off = 32; off >= 1; off >>= 1)
        s += __shfl_xor(s, off, 64);
    if (lane == 0) red[4 + wid] = s;
    __syncthreads();
    const float S = red[4] + red[5] + red[6] + red[7];

    const float r = 1.0f / (S + 1e-8f);
    alpha[(size_t)b * KP + tid]       = a0 * r;
    alpha[(size_t)b * KP + tid + 256] = a1 * r;
}

extern "C" void kernel_launch(void* const* d_in, const int* in_sizes, int n_in,
                              void* d_out, int out_size, void* d_ws, size_t ws_size,
                              hipStream_t stream) {
    const float* z        = (const float*)d_in[0];
    const float* mu       = (const float*)d_in[1];
    const float* log_diag = (const float*)d_in[2];
    const float* log_s    = (const float*)d_in[3];
    const float* lod      = (const float*)d_in[4];
    float* out = (float*)d_out;

    char* ws = (char*)d_ws;
    unsigned short* Limg = (unsigned short*)ws;                 // 8 MB
    float* wws    = (float*)(ws + (size_t)KP * 16384);          // 128 KB
    float* biasws = wws + (size_t)KP * 64;                      // 2 KB
    float* mahalws = biasws + KP;                               // 8 MB

    prep_kernel<<<KP, 256, 0, stream>>>(mu, log_diag, log_s, lod, Limg, wws, biasws);
    mahal_kernel<<<512, 256, 0, stream>>>(z, Limg, wws, mahalws);
    softmax_kernel<<<BB, 256, 0, stream>>>(mahalws, biasws, out);
}